// Round 2
// baseline (286.581 us; speedup 1.0000x reference)
//
#include <hip/hip_runtime.h>
#include <hip/hip_bf16.h>

typedef short short8 __attribute__((ext_vector_type(8)));
typedef float f32x4 __attribute__((ext_vector_type(4)));
typedef int int4v __attribute__((ext_vector_type(4)));
typedef unsigned short ushort4v __attribute__((ext_vector_type(4)));

#define NB 4
#define NS 4096
#define NE 128
#define ALPHA 0.1275174468f  /* log2(e)/sqrt(128) */

static __device__ __forceinline__ unsigned short f2bf(float f) {
  union { float f; unsigned int u; } v; v.f = f;
  unsigned int u = v.u;
  return (unsigned short)((u + 0x7FFFu + ((u >> 16) & 1u)) >> 16);
}

// ---------------------------------------------------------------------------
// Kernel 0: one-time f32 -> bf16 conversion of the three weight matrices.
// 3 x 128 x 128 floats = 12288 float4 units; 48 blocks x 256 threads.
// ---------------------------------------------------------------------------
__global__ __launch_bounds__(256) void prep_k(
    const float* __restrict__ Wq, const float* __restrict__ Wk,
    const float* __restrict__ Wv,
    unsigned short* __restrict__ Wqb, unsigned short* __restrict__ Wkb,
    unsigned short* __restrict__ Wvb) {
  int i = blockIdx.x * 256 + threadIdx.x;          // 0..12287
  const float* srcs[3] = {Wq, Wk, Wv};
  unsigned short* dsts[3] = {Wqb, Wkb, Wvb};
  int m = i >> 12, off = (i & 4095) * 4;
  float4 v = *(const float4*)(srcs[m] + off);
  ushort4v o;
  o[0] = f2bf(v.x); o[1] = f2bf(v.y); o[2] = f2bf(v.z); o[3] = f2bf(v.w);
  *(ushort4v*)(dsts[m] + off) = o;
}

static __device__ __forceinline__ f32x4 wtile(const short8 xa[4],
                                              const unsigned short* __restrict__ Wb,
                                              int fb, int g, int li) {
  f32x4 acc = {0.f, 0.f, 0.f, 0.f};
  #pragma unroll
  for (int ks = 0; ks < 4; ++ks) {
    short8 wf = *(const short8*)(Wb + (fb * 16 + li) * NE + ks * 32 + g * 8);
    acc = __builtin_amdgcn_mfma_f32_16x16x32_bf16(xa[ks], wf, acc, 0, 0, 0);
  }
  return acc;
}

// ---------------------------------------------------------------------------
// Kernel 1: fused QKV projection (f32 in, bf16 staged out).
//  Qs[b,n,e] = (X@Wq^T + bq) * ALPHA        (bf16, row-major, exp2 units)
//  K [b,n,e] = (X@Wk^T + bk)                (bf16, row-major)
//  VT[b,e,n] = (X@Wv^T + bv) transposed     (bf16)  -> PV A-frags contiguous
// ---------------------------------------------------------------------------
__global__ __launch_bounds__(256) void qkv_proj_k(
    const float* __restrict__ X,
    const unsigned short* __restrict__ Wqb, const float* __restrict__ bq,
    const unsigned short* __restrict__ Wkb, const float* __restrict__ bk,
    const unsigned short* __restrict__ Wvb, const float* __restrict__ bv,
    unsigned short* __restrict__ Qs, unsigned short* __restrict__ Kd,
    unsigned short* __restrict__ VT) {
  const int lane = threadIdx.x & 63;
  const int wv   = threadIdx.x >> 6;
  const int tile = blockIdx.x * 4 + wv;          // 0..1023
  const int m0   = tile * 16;
  const int g    = lane >> 4, li = lane & 15;

  // A-frags of X tile: A[row=li][k=e], converted f32 -> bf16 (RNE)
  short8 xa[4];
  #pragma unroll
  for (int ks = 0; ks < 4; ++ks) {
    const float* xp = X + (size_t)(m0 + li) * NE + ks * 32 + g * 8;
    float4 x0 = *(const float4*)xp;
    float4 x1 = *(const float4*)(xp + 4);
    short8 t;
    t[0] = (short)f2bf(x0.x); t[1] = (short)f2bf(x0.y);
    t[2] = (short)f2bf(x0.z); t[3] = (short)f2bf(x0.w);
    t[4] = (short)f2bf(x1.x); t[5] = (short)f2bf(x1.y);
    t[6] = (short)f2bf(x1.z); t[7] = (short)f2bf(x1.w);
    xa[ks] = t;
  }

  const int bb = m0 >> 12;                // batch
  const int n0 = (m0 & 4095) + g * 4;     // within-batch row base for VT store

  #pragma unroll
  for (int fb = 0; fb < 8; ++fb) {
    // ---- Q (pre-scaled into exp2 units) ----
    f32x4 aq = wtile(xa, Wqb, fb, g, li);
    float biq = bq[fb * 16 + li];
    #pragma unroll
    for (int r = 0; r < 4; ++r)
      Qs[(size_t)(m0 + g * 4 + r) * NE + fb * 16 + li] = f2bf((aq[r] + biq) * ALPHA);
    // ---- K ----
    f32x4 ak = wtile(xa, Wkb, fb, g, li);
    float bik = bk[fb * 16 + li];
    #pragma unroll
    for (int r = 0; r < 4; ++r)
      Kd[(size_t)(m0 + g * 4 + r) * NE + fb * 16 + li] = f2bf(ak[r] + bik);
    // ---- V, stored transposed: VT[b][f][n] ----
    f32x4 av = wtile(xa, Wvb, fb, g, li);
    float biv = bv[fb * 16 + li];
    ushort4v pv;
    #pragma unroll
    for (int r = 0; r < 4; ++r) pv[r] = f2bf(av[r] + biv);
    *(ushort4v*)(VT + (size_t)bb * (NE * NS) + (size_t)(fb * 16 + li) * NS + n0) = pv;
  }
}

// ---------------------------------------------------------------------------
// Kernel 2: flash attention (full, non-causal), swapped orientation.
// Per wave: 16 q-rows. S^T = mfma(A=K, B=Q) -> lane owns q-row i = lane&15.
// Online softmax in exp2 units (Q pre-scaled). P redistributed to PV B-frags
// with 8 shuffles. O accumulated as O^T = mfma(A=VT, B=P^T). No LDS/barriers.
// Block->batch mapping keyed to blockIdx so each XCD L2 sees one batch.
// ---------------------------------------------------------------------------
__global__ __launch_bounds__(256) void attn_k(
    const unsigned short* __restrict__ Qs, const unsigned short* __restrict__ Kd,
    const unsigned short* __restrict__ VT, float* __restrict__ Out) {
  const int lane = threadIdx.x & 63;
  const int wv   = threadIdx.x >> 6;
  const int bi   = blockIdx.x;
  const int b    = (bi >> 1) & 3;                      // batch, tied to XCD pair
  const int widb = ((bi >> 3) << 1) | (bi & 1);        // 0..63 within batch
  const int qb   = (widb * 4 + wv) * 16;               // q-row tile base
  const int g    = lane >> 4, li = lane & 15;

  // Q B-frags: B[k=e][col=i=li]
  const unsigned short* Qrow = Qs + (size_t)(b * NS + qb + li) * NE + g * 8;
  short8 qf[4];
  #pragma unroll
  for (int ks = 0; ks < 4; ++ks) qf[ks] = *(const short8*)(Qrow + ks * 32);

  const unsigned short* Kb  = Kd + (size_t)b * (NS * NE);
  const unsigned short* VTb = VT + (size_t)b * (NE * NS);

  f32x4 o[8];
  #pragma unroll
  for (int et = 0; et < 8; ++et) o[et] = (f32x4){0.f, 0.f, 0.f, 0.f};
  float m2 = -1e30f, L = 0.f;

  const int l0 = ((g & 1) << 5) + li;   // shuffle source lanes for P exchange
  const int l1 = l0 + 16;

  for (int kt = 0; kt < NS / 32; ++kt) {
    const int j0 = kt * 32;
    // ---- S^T tile: 2 j-subtiles of 16, K=128 in 4 MFMA steps each ----
    f32x4 s[2];
    #pragma unroll
    for (int jt = 0; jt < 2; ++jt) {
      s[jt] = (f32x4){0.f, 0.f, 0.f, 0.f};
      const unsigned short* Krow = Kb + (size_t)(j0 + jt * 16 + li) * NE + g * 8;
      #pragma unroll
      for (int ks = 0; ks < 4; ++ks) {
        short8 kf = *(const short8*)(Krow + ks * 32);
        s[jt] = __builtin_amdgcn_mfma_f32_16x16x32_bf16(kf, qf[ks], s[jt], 0, 0, 0);
      }
    }
    // lane holds S2[i=qb+li][j = j0 + 16*jt + 4*g + r]  (log2-scaled logits)

    // ---- online softmax (row i per lane, replicated over g) ----
    float tm = fmaxf(fmaxf(fmaxf(s[0][0], s[0][1]), fmaxf(s[0][2], s[0][3])),
                     fmaxf(fmaxf(s[1][0], s[1][1]), fmaxf(s[1][2], s[1][3])));
    tm = fmaxf(tm, __shfl_xor(tm, 16));
    tm = fmaxf(tm, __shfl_xor(tm, 32));
    float mn = fmaxf(m2, tm);
    float c  = __builtin_amdgcn_exp2f(m2 - mn);
    float p[2][4];
    float ts = 0.f;
    #pragma unroll
    for (int jt = 0; jt < 2; ++jt)
      #pragma unroll
      for (int r = 0; r < 4; ++r) {
        p[jt][r] = __builtin_amdgcn_exp2f(s[jt][r] - mn);
        ts += p[jt][r];
      }
    ts += __shfl_xor(ts, 16);
    ts += __shfl_xor(ts, 32);
    L  = L * c + ts;
    m2 = mn;
    #pragma unroll
    for (int et = 0; et < 8; ++et) o[et] = o[et] * c;

    // ---- pack P to bf16 pairs and redistribute into PV B-frags ----
    unsigned int pk[2][2];
    #pragma unroll
    for (int jt = 0; jt < 2; ++jt) {
      pk[jt][0] = (unsigned int)f2bf(p[jt][0]) | ((unsigned int)f2bf(p[jt][1]) << 16);
      pk[jt][1] = (unsigned int)f2bf(p[jt][2]) | ((unsigned int)f2bf(p[jt][3]) << 16);
    }
    int w0, w1, w2, w3, ta, tb;
    ta = __shfl((int)pk[0][0], l0); tb = __shfl((int)pk[1][0], l0); w0 = (g < 2) ? ta : tb;
    ta = __shfl((int)pk[0][1], l0); tb = __shfl((int)pk[1][1], l0); w1 = (g < 2) ? ta : tb;
    ta = __shfl((int)pk[0][0], l1); tb = __shfl((int)pk[1][0], l1); w2 = (g < 2) ? ta : tb;
    ta = __shfl((int)pk[0][1], l1); tb = __shfl((int)pk[1][1], l1); w3 = (g < 2) ? ta : tb;
    union { int4v i4; short8 s8; } pb;
    pb.i4 = (int4v){w0, w1, w2, w3};   // B[k=j][col=i]: lane needs P[i][8g..8g+7]

    // ---- PV: O^T += mfma(A=VT (row e, k=j), B=P^T) ----
    #pragma unroll
    for (int et = 0; et < 8; ++et) {
      short8 vf = *(const short8*)(VTb + (size_t)(et * 16 + li) * NS + j0 + g * 8);
      o[et] = __builtin_amdgcn_mfma_f32_16x16x32_bf16(vf, pb.s8, o[et], 0, 0, 0);
    }
  }

  // ---- epilogue: divide by L, store O[b, qb+li, e] as f32 ----
  const float rL = 1.f / L;
  float* Orow = Out + (size_t)(b * NS + qb + li) * NE;
  #pragma unroll
  for (int et = 0; et < 8; ++et) {
    float4 v;
    v.x = o[et][0] * rL; v.y = o[et][1] * rL;
    v.z = o[et][2] * rL; v.w = o[et][3] * rL;
    *(float4*)(Orow + et * 16 + g * 4) = v;
  }
}

extern "C" void kernel_launch(void* const* d_in, const int* in_sizes, int n_in,
                              void* d_out, int out_size, void* d_ws, size_t ws_size,
                              hipStream_t stream) {
  const float* X  = (const float*)d_in[0];
  // d_in[1] = context : unused (per-row bias is softmax-invariant)
  const float* Wq = (const float*)d_in[2];
  const float* bq = (const float*)d_in[3];
  const float* Wk = (const float*)d_in[4];
  const float* bk = (const float*)d_in[5];
  const float* Wv = (const float*)d_in[6];
  const float* bv = (const float*)d_in[7];
  // d_in[8] = Wc, d_in[9] = bc : unused

  unsigned short* Qs  = (unsigned short*)d_ws;                // 4 MB
  unsigned short* Kd  = Qs + (size_t)NB * NS * NE;            // 4 MB
  unsigned short* VT  = Kd + (size_t)NB * NS * NE;            // 4 MB
  unsigned short* Wqb = VT + (size_t)NB * NS * NE;            // 32 KB
  unsigned short* Wkb = Wqb + NE * NE;
  unsigned short* Wvb = Wkb + NE * NE;

  prep_k<<<48, 256, 0, stream>>>(Wq, Wk, Wv, Wqb, Wkb, Wvb);
  qkv_proj_k<<<256, 256, 0, stream>>>(X, Wqb, bq, Wkb, bk, Wvb, bv, Qs, Kd, VT);
  attn_k<<<256, 256, 0, stream>>>(Qs, Kd, VT, (float*)d_out);
}

// Round 4
// 264.383 us; speedup vs baseline: 1.0840x; 1.0840x over previous
//
#include <hip/hip_runtime.h>
#include <hip/hip_bf16.h>

typedef short short8 __attribute__((ext_vector_type(8)));
typedef float f32x4 __attribute__((ext_vector_type(4)));
typedef int int4v __attribute__((ext_vector_type(4)));
typedef unsigned short ushort4v __attribute__((ext_vector_type(4)));

#define NB 4
#define NS 4096
#define NE 128
#define ALPHA 0.1275174468f  /* log2(e)/sqrt(128) */
#define SPLITS 4
#define KSPLIT (NS / SPLITS)   /* 1024 keys per split-wave */
#define KVB 64                 /* keys per inner iteration */

static __device__ __forceinline__ unsigned short f2bf(float f) {
  union { float f; unsigned int u; } v; v.f = f;
  unsigned int u = v.u;
  return (unsigned short)((u + 0x7FFFu + ((u >> 16) & 1u)) >> 16);
}

// ---------------------------------------------------------------------------
// Kernel 0: one-time f32 -> bf16 conversion of the three weight matrices.
// ---------------------------------------------------------------------------
__global__ __launch_bounds__(256) void prep_k(
    const float* __restrict__ Wq, const float* __restrict__ Wk,
    const float* __restrict__ Wv,
    unsigned short* __restrict__ Wqb, unsigned short* __restrict__ Wkb,
    unsigned short* __restrict__ Wvb) {
  int i = blockIdx.x * 256 + threadIdx.x;          // 0..12287
  const float* srcs[3] = {Wq, Wk, Wv};
  unsigned short* dsts[3] = {Wqb, Wkb, Wvb};
  int m = i >> 12, off = (i & 4095) * 4;
  float4 v = *(const float4*)(srcs[m] + off);
  ushort4v o;
  o[0] = f2bf(v.x); o[1] = f2bf(v.y); o[2] = f2bf(v.z); o[3] = f2bf(v.w);
  *(ushort4v*)(dsts[m] + off) = o;
}

static __device__ __forceinline__ f32x4 wtile(const short8 xa[4],
                                              const unsigned short* __restrict__ Wb,
                                              int fb, int g, int li) {
  f32x4 acc = {0.f, 0.f, 0.f, 0.f};
  #pragma unroll
  for (int ks = 0; ks < 4; ++ks) {
    short8 wf = *(const short8*)(Wb + (fb * 16 + li) * NE + ks * 32 + g * 8);
    acc = __builtin_amdgcn_mfma_f32_16x16x32_bf16(xa[ks], wf, acc, 0, 0, 0);
  }
  return acc;
}

// ---------------------------------------------------------------------------
// Kernel 1: fused QKV projection (f32 in, bf16 staged out).
//  Qs[b,n,e] = (X@Wq^T + bq) * ALPHA   (bf16, exp2 units)
//  K [b,n,e] = (X@Wk^T + bk)
//  VT[b,e,n] = (X@Wv^T + bv) transposed
// ---------------------------------------------------------------------------
__global__ __launch_bounds__(256) void qkv_proj_k(
    const float* __restrict__ X,
    const unsigned short* __restrict__ Wqb, const float* __restrict__ bq,
    const unsigned short* __restrict__ Wkb, const float* __restrict__ bk,
    const unsigned short* __restrict__ Wvb, const float* __restrict__ bv,
    unsigned short* __restrict__ Qs, unsigned short* __restrict__ Kd,
    unsigned short* __restrict__ VT) {
  const int lane = threadIdx.x & 63;
  const int wv   = threadIdx.x >> 6;
  const int tile = blockIdx.x * 4 + wv;          // 0..1023
  const int m0   = tile * 16;
  const int g    = lane >> 4, li = lane & 15;

  short8 xa[4];
  #pragma unroll
  for (int ks = 0; ks < 4; ++ks) {
    const float* xp = X + (size_t)(m0 + li) * NE + ks * 32 + g * 8;
    float4 x0 = *(const float4*)xp;
    float4 x1 = *(const float4*)(xp + 4);
    short8 t;
    t[0] = (short)f2bf(x0.x); t[1] = (short)f2bf(x0.y);
    t[2] = (short)f2bf(x0.z); t[3] = (short)f2bf(x0.w);
    t[4] = (short)f2bf(x1.x); t[5] = (short)f2bf(x1.y);
    t[6] = (short)f2bf(x1.z); t[7] = (short)f2bf(x1.w);
    xa[ks] = t;
  }

  const int bb = m0 >> 12;
  const int n0 = (m0 & 4095) + g * 4;

  #pragma unroll
  for (int fb = 0; fb < 8; ++fb) {
    f32x4 aq = wtile(xa, Wqb, fb, g, li);
    float biq = bq[fb * 16 + li];
    #pragma unroll
    for (int r = 0; r < 4; ++r)
      Qs[(size_t)(m0 + g * 4 + r) * NE + fb * 16 + li] = f2bf((aq[r] + biq) * ALPHA);
    f32x4 ak = wtile(xa, Wkb, fb, g, li);
    float bik = bk[fb * 16 + li];
    #pragma unroll
    for (int r = 0; r < 4; ++r)
      Kd[(size_t)(m0 + g * 4 + r) * NE + fb * 16 + li] = f2bf(ak[r] + bik);
    f32x4 av = wtile(xa, Wvb, fb, g, li);
    float biv = bv[fb * 16 + li];
    ushort4v pv;
    #pragma unroll
    for (int r = 0; r < 4; ++r) pv[r] = f2bf(av[r] + biv);
    *(ushort4v*)(VT + (size_t)bb * (NE * NS) + (size_t)(fb * 16 + li) * NS + n0) = pv;
  }
}

// ---------------------------------------------------------------------------
// Kernel 2: flash attention, in-block split-K.
// 512 threads = 8 waves = 2 q-tiles x 4 key-splits (1024 keys each).
// Per wave: 16 q-rows, swapped orientation (lane owns q-row i = lane&15),
// KVB=64 keys/iter, fresh-max online softmax every iteration (round-2-proven
// numerics), per-lane partial L. Partials combined in LDS at block end.
// ---------------------------------------------------------------------------
__global__ __launch_bounds__(512, 4) void attn_k(
    const unsigned short* __restrict__ Qs, const unsigned short* __restrict__ Kd,
    const unsigned short* __restrict__ VT, float* __restrict__ Out) {
  __shared__ float4 smO[2][SPLITS][8][64];     // 64 KB
  __shared__ float  smML[2][SPLITS][2][16];    // 1 KB

  const int lane = threadIdx.x & 63;
  const int wv   = threadIdx.x >> 6;           // 0..7
  const int qtw  = wv >> 2;                    // q-tile within block (0..1)
  const int sp   = wv & 3;                     // key split (0..3)
  const int bi   = blockIdx.x;                 // 0..511
  const int b    = (bi >> 1) & 3;              // batch tied to XCD pair
  const int within = ((bi >> 3) << 1) | (bi & 1);   // 0..127
  const int qt   = within * 2 + qtw;           // within-batch q-tile 0..255
  const int qb   = qt * 16;
  const int g    = lane >> 4, li = lane & 15;

  // Q B-frags: B[k=e][col=i=li]
  const unsigned short* Qrow = Qs + (size_t)(b * NS + qb + li) * NE + g * 8;
  short8 qf[4];
  #pragma unroll
  for (int ks = 0; ks < 4; ++ks) qf[ks] = *(const short8*)(Qrow + ks * 32);

  const unsigned short* Kb  = Kd + (size_t)b * (NS * NE) + (size_t)sp * KSPLIT * NE;
  const unsigned short* VTb = VT + (size_t)b * (NE * NS) + sp * KSPLIT;

  f32x4 o[8];
  #pragma unroll
  for (int et = 0; et < 8; ++et) o[et] = (f32x4){0.f, 0.f, 0.f, 0.f};
  float m2 = -1e30f, Lp = 0.f;                 // running max (log2), per-lane partial L

  const int l0 = ((g & 1) << 5) + li;          // shuffle source lanes
  const int l1 = l0 + 16;

  for (int it = 0; it < KSPLIT / KVB; ++it) {
    const int j0 = it * KVB;
    // ---- S^T: 4 j-subtiles of 16, K=128 in 4 MFMA steps each ----
    f32x4 s[4];
    #pragma unroll
    for (int jt = 0; jt < 4; ++jt) {
      s[jt] = (f32x4){0.f, 0.f, 0.f, 0.f};
      const unsigned short* Krow = Kb + (size_t)(j0 + jt * 16 + li) * NE + g * 8;
      #pragma unroll
      for (int ks = 0; ks < 4; ++ks) {
        short8 kf = *(const short8*)(Krow + ks * 32);
        s[jt] = __builtin_amdgcn_mfma_f32_16x16x32_bf16(kf, qf[ks], s[jt], 0, 0, 0);
      }
    }
    // lane holds S[i=li][j = j0 + 16*jt + 4*g + r] (log2-scaled logits)

    // ---- fresh-max online softmax (row i per lane, replicated over g) ----
    float tm = fmaxf(fmaxf(fmaxf(s[0][0], s[0][1]), fmaxf(s[0][2], s[0][3])),
                     fmaxf(fmaxf(s[1][0], s[1][1]), fmaxf(s[1][2], s[1][3])));
    tm = fmaxf(tm, fmaxf(fmaxf(fmaxf(s[2][0], s[2][1]), fmaxf(s[2][2], s[2][3])),
                         fmaxf(fmaxf(s[3][0], s[3][1]), fmaxf(s[3][2], s[3][3]))));
    tm = fmaxf(tm, __shfl_xor(tm, 16));
    tm = fmaxf(tm, __shfl_xor(tm, 32));
    float mn = fmaxf(m2, tm);
    float c  = __builtin_amdgcn_exp2f(m2 - mn);
    #pragma unroll
    for (int et = 0; et < 8; ++et) o[et] = o[et] * c;
    m2 = mn;

    // ---- P = exp2(S - m2) <= 1, pack to bf16 pairs (manual RNE) ----
    unsigned int pk[4][2];
    float ts = 0.f;
    #pragma unroll
    for (int jt = 0; jt < 4; ++jt) {
      float p0 = __builtin_amdgcn_exp2f(s[jt][0] - m2);
      float p1 = __builtin_amdgcn_exp2f(s[jt][1] - m2);
      float p2 = __builtin_amdgcn_exp2f(s[jt][2] - m2);
      float p3 = __builtin_amdgcn_exp2f(s[jt][3] - m2);
      ts += (p0 + p1) + (p2 + p3);
      pk[jt][0] = (unsigned int)f2bf(p0) | ((unsigned int)f2bf(p1) << 16);
      pk[jt][1] = (unsigned int)f2bf(p2) | ((unsigned int)f2bf(p3) << 16);
    }
    Lp = Lp * c + ts;

    // ---- redistribute P into two PV B-frags (16 shfl + 8 sel) ----
    int ta, tb, w0, w1, w2, w3;
    union { int4v i4; short8 s8; } pb0, pb1;
    ta = __shfl((int)pk[0][0], l0); tb = __shfl((int)pk[1][0], l0); w0 = (g < 2) ? ta : tb;
    ta = __shfl((int)pk[0][1], l0); tb = __shfl((int)pk[1][1], l0); w1 = (g < 2) ? ta : tb;
    ta = __shfl((int)pk[0][0], l1); tb = __shfl((int)pk[1][0], l1); w2 = (g < 2) ? ta : tb;
    ta = __shfl((int)pk[0][1], l1); tb = __shfl((int)pk[1][1], l1); w3 = (g < 2) ? ta : tb;
    pb0.i4 = (int4v){w0, w1, w2, w3};
    ta = __shfl((int)pk[2][0], l0); tb = __shfl((int)pk[3][0], l0); w0 = (g < 2) ? ta : tb;
    ta = __shfl((int)pk[2][1], l0); tb = __shfl((int)pk[3][1], l0); w1 = (g < 2) ? ta : tb;
    ta = __shfl((int)pk[2][0], l1); tb = __shfl((int)pk[3][0], l1); w2 = (g < 2) ? ta : tb;
    ta = __shfl((int)pk[2][1], l1); tb = __shfl((int)pk[3][1], l1); w3 = (g < 2) ? ta : tb;
    pb1.i4 = (int4v){w0, w1, w2, w3};

    // ---- PV: O^T += VT(:, j0..j0+63) @ P^T ----
    #pragma unroll
    for (int et = 0; et < 8; ++et) {
      const unsigned short* Vrow = VTb + (size_t)(et * 16 + li) * NS + j0 + g * 8;
      short8 vf0 = *(const short8*)(Vrow);
      o[et] = __builtin_amdgcn_mfma_f32_16x16x32_bf16(vf0, pb0.s8, o[et], 0, 0, 0);
      short8 vf1 = *(const short8*)(Vrow + 32);
      o[et] = __builtin_amdgcn_mfma_f32_16x16x32_bf16(vf1, pb1.s8, o[et], 0, 0, 0);
    }
  }

  // ---- epilogue: publish partials to LDS ----
  Lp += __shfl_xor(Lp, 16);
  Lp += __shfl_xor(Lp, 32);          // row-sum, replicated across g
  #pragma unroll
  for (int et = 0; et < 8; ++et) {
    float4 v; v.x = o[et][0]; v.y = o[et][1]; v.z = o[et][2]; v.w = o[et][3];
    smO[qtw][sp][et][lane] = v;
  }
  if (lane < 16) {
    smML[qtw][sp][0][lane] = m2;
    smML[qtw][sp][1][lane] = Lp;
  }
  __syncthreads();

  // ---- combine: wave wv handles q-tile (wv>>2), et pair (wv&3)*2 ----
  const int cqt  = wv >> 2;
  const int cet0 = (wv & 3) * 2;
  float ms[SPLITS], Ls[SPLITS];
  #pragma unroll
  for (int s2 = 0; s2 < SPLITS; ++s2) {
    ms[s2] = smML[cqt][s2][0][li];
    Ls[s2] = smML[cqt][s2][1][li];
  }
  float M = fmaxf(fmaxf(ms[0], ms[1]), fmaxf(ms[2], ms[3]));
  float W[SPLITS], Ltot = 0.f;
  #pragma unroll
  for (int s2 = 0; s2 < SPLITS; ++s2) {
    W[s2] = __builtin_amdgcn_exp2f(ms[s2] - M);
    Ltot += W[s2] * Ls[s2];
  }
  const float rL = 1.f / Ltot;
  const int orow = b * NS + (within * 2 + cqt) * 16 + li;
  #pragma unroll
  for (int e2 = 0; e2 < 2; ++e2) {
    const int et = cet0 + e2;
    float4 acc = make_float4(0.f, 0.f, 0.f, 0.f);
    #pragma unroll
    for (int s2 = 0; s2 < SPLITS; ++s2) {
      float4 v = smO[cqt][s2][et][lane];
      acc.x += W[s2] * v.x; acc.y += W[s2] * v.y;
      acc.z += W[s2] * v.z; acc.w += W[s2] * v.w;
    }
    acc.x *= rL; acc.y *= rL; acc.z *= rL; acc.w *= rL;
    *(float4*)(Out + (size_t)orow * NE + et * 16 + g * 4) = acc;
  }
}

extern "C" void kernel_launch(void* const* d_in, const int* in_sizes, int n_in,
                              void* d_out, int out_size, void* d_ws, size_t ws_size,
                              hipStream_t stream) {
  const float* X  = (const float*)d_in[0];
  // d_in[1] = context : unused (per-row bias is softmax-invariant)
  const float* Wq = (const float*)d_in[2];
  const float* bq = (const float*)d_in[3];
  const float* Wk = (const float*)d_in[4];
  const float* bk = (const float*)d_in[5];
  const float* Wv = (const float*)d_in[6];
  const float* bv = (const float*)d_in[7];
  // d_in[8] = Wc, d_in[9] = bc : unused

  unsigned short* Qs  = (unsigned short*)d_ws;                // 4 MB
  unsigned short* Kd  = Qs + (size_t)NB * NS * NE;            // 4 MB
  unsigned short* VT  = Kd + (size_t)NB * NS * NE;            // 4 MB
  unsigned short* Wqb = VT + (size_t)NB * NS * NE;            // 32 KB x3
  unsigned short* Wkb = Wqb + NE * NE;
  unsigned short* Wvb = Wkb + NE * NE;

  prep_k<<<48, 256, 0, stream>>>(Wq, Wk, Wv, Wqb, Wkb, Wvb);
  qkv_proj_k<<<256, 256, 0, stream>>>(X, Wqb, bq, Wkb, bk, Wvb, bv, Qs, Kd, VT);
  attn_k<<<512, 512, 0, stream>>>(Qs, Kd, VT, (float*)d_out);
}

// Round 5
// 259.431 us; speedup vs baseline: 1.1046x; 1.0191x over previous
//
#include <hip/hip_runtime.h>
#include <hip/hip_bf16.h>

typedef short short8 __attribute__((ext_vector_type(8)));
typedef float f32x4 __attribute__((ext_vector_type(4)));
typedef int int4v __attribute__((ext_vector_type(4)));
typedef unsigned short ushort4v __attribute__((ext_vector_type(4)));

#define NB 4
#define NS 4096
#define NE 128
#define ALPHA 0.1275174468f  /* log2(e)/sqrt(128) */
#define SPLITS 4
#define KSPLIT (NS / SPLITS)   /* 1024 keys per split-wave */
#define KVB 64                 /* keys per inner iteration */
#define NIT (KSPLIT / KVB)     /* 16 */

static __device__ __forceinline__ unsigned short f2bf(float f) {
  union { float f; unsigned int u; } v; v.f = f;
  unsigned int u = v.u;
  return (unsigned short)((u + 0x7FFFu + ((u >> 16) & 1u)) >> 16);
}

// ---------------------------------------------------------------------------
// Kernel 0: one-time f32 -> bf16 conversion of the three weight matrices.
// ---------------------------------------------------------------------------
__global__ __launch_bounds__(256) void prep_k(
    const float* __restrict__ Wq, const float* __restrict__ Wk,
    const float* __restrict__ Wv,
    unsigned short* __restrict__ Wqb, unsigned short* __restrict__ Wkb,
    unsigned short* __restrict__ Wvb) {
  int i = blockIdx.x * 256 + threadIdx.x;          // 0..12287
  const float* srcs[3] = {Wq, Wk, Wv};
  unsigned short* dsts[3] = {Wqb, Wkb, Wvb};
  int m = i >> 12, off = (i & 4095) * 4;
  float4 v = *(const float4*)(srcs[m] + off);
  ushort4v o;
  o[0] = f2bf(v.x); o[1] = f2bf(v.y); o[2] = f2bf(v.z); o[3] = f2bf(v.w);
  *(ushort4v*)(dsts[m] + off) = o;
}

static __device__ __forceinline__ f32x4 wtile(const short8 xa[4],
                                              const unsigned short* __restrict__ Wb,
                                              int fb, int g, int li) {
  f32x4 acc = {0.f, 0.f, 0.f, 0.f};
  #pragma unroll
  for (int ks = 0; ks < 4; ++ks) {
    short8 wf = *(const short8*)(Wb + (fb * 16 + li) * NE + ks * 32 + g * 8);
    acc = __builtin_amdgcn_mfma_f32_16x16x32_bf16(xa[ks], wf, acc, 0, 0, 0);
  }
  return acc;
}

// ---------------------------------------------------------------------------
// Kernel 1: fused QKV projection (f32 in, bf16 staged out).
// 512 blocks: each covers one 16-row tile half (fb 0-3 or 4-7) -> 2 waves/SIMD.
// ---------------------------------------------------------------------------
__global__ __launch_bounds__(256) void qkv_proj_k(
    const float* __restrict__ X,
    const unsigned short* __restrict__ Wqb, const float* __restrict__ bq,
    const unsigned short* __restrict__ Wkb, const float* __restrict__ bk,
    const unsigned short* __restrict__ Wvb, const float* __restrict__ bv,
    unsigned short* __restrict__ Qs, unsigned short* __restrict__ Kd,
    unsigned short* __restrict__ VT) {
  const int lane = threadIdx.x & 63;
  const int wv   = threadIdx.x >> 6;
  const int tile = (blockIdx.x >> 1) * 4 + wv;   // 0..1023
  const int fb0  = (blockIdx.x & 1) * 4;         // output half
  const int m0   = tile * 16;
  const int g    = lane >> 4, li = lane & 15;

  short8 xa[4];
  #pragma unroll
  for (int ks = 0; ks < 4; ++ks) {
    const float* xp = X + (size_t)(m0 + li) * NE + ks * 32 + g * 8;
    float4 x0 = *(const float4*)xp;
    float4 x1 = *(const float4*)(xp + 4);
    short8 t;
    t[0] = (short)f2bf(x0.x); t[1] = (short)f2bf(x0.y);
    t[2] = (short)f2bf(x0.z); t[3] = (short)f2bf(x0.w);
    t[4] = (short)f2bf(x1.x); t[5] = (short)f2bf(x1.y);
    t[6] = (short)f2bf(x1.z); t[7] = (short)f2bf(x1.w);
    xa[ks] = t;
  }

  const int bb = m0 >> 12;
  const int n0 = (m0 & 4095) + g * 4;

  #pragma unroll
  for (int f2 = 0; f2 < 4; ++f2) {
    const int fb = fb0 + f2;
    f32x4 aq = wtile(xa, Wqb, fb, g, li);
    float biq = bq[fb * 16 + li];
    #pragma unroll
    for (int r = 0; r < 4; ++r)
      Qs[(size_t)(m0 + g * 4 + r) * NE + fb * 16 + li] = f2bf((aq[r] + biq) * ALPHA);
    f32x4 ak = wtile(xa, Wkb, fb, g, li);
    float bik = bk[fb * 16 + li];
    #pragma unroll
    for (int r = 0; r < 4; ++r)
      Kd[(size_t)(m0 + g * 4 + r) * NE + fb * 16 + li] = f2bf(ak[r] + bik);
    f32x4 av = wtile(xa, Wvb, fb, g, li);
    float biv = bv[fb * 16 + li];
    ushort4v pv;
    #pragma unroll
    for (int r = 0; r < 4; ++r) pv[r] = f2bf(av[r] + biv);
    *(ushort4v*)(VT + (size_t)bb * (NE * NS) + (size_t)(fb * 16 + li) * NS + n0) = pv;
  }
}

// ---------------------------------------------------------------------------
// Kernel 2: flash attention, in-block split-K, register double-buffered.
// 512 threads = 8 waves = 2 q-tiles x 4 key-splits (1024 keys each).
// Pipeline per iter: issue V loads -> QK from resident K regs (counted vmcnt)
// -> issue next K loads -> softmax/pack/exchange -> PV.
// ---------------------------------------------------------------------------
__global__ __launch_bounds__(512, 2) void attn_k(
    const unsigned short* __restrict__ Qs, const unsigned short* __restrict__ Kd,
    const unsigned short* __restrict__ VT, float* __restrict__ Out) {
  __shared__ float4 smO[2][SPLITS][8][64];     // 64 KB
  __shared__ float  smML[2][SPLITS][2][16];    // 1 KB

  const int lane = threadIdx.x & 63;
  const int wv   = threadIdx.x >> 6;           // 0..7
  const int qtw  = wv >> 2;                    // q-tile within block (0..1)
  const int sp   = wv & 3;                     // key split (0..3)
  const int bi   = blockIdx.x;                 // 0..511
  const int b    = (bi >> 1) & 3;              // batch tied to XCD pair
  const int within = ((bi >> 3) << 1) | (bi & 1);   // 0..127
  const int qt   = within * 2 + qtw;           // within-batch q-tile 0..255
  const int qb   = qt * 16;
  const int g    = lane >> 4, li = lane & 15;

  // Q B-frags: B[k=e][col=i=li]
  const unsigned short* Qrow = Qs + (size_t)(b * NS + qb + li) * NE + g * 8;
  short8 qf[4];
  #pragma unroll
  for (int ks = 0; ks < 4; ++ks) qf[ks] = *(const short8*)(Qrow + ks * 32);

  const unsigned short* Kb  = Kd + (size_t)b * (NS * NE) + (size_t)sp * KSPLIT * NE;
  const unsigned short* VTb = VT + (size_t)b * (NE * NS) + sp * KSPLIT;

  f32x4 o[8];
  #pragma unroll
  for (int et = 0; et < 8; ++et) o[et] = (f32x4){0.f, 0.f, 0.f, 0.f};
  float m2 = -1e30f, Lp = 0.f;                 // running max (log2), per-lane partial L

  const int l0 = ((g & 1) << 5) + li;          // shuffle source lanes
  const int l1 = l0 + 16;

  // ---- preload K tile for it=0 into registers ----
  short8 kf[4][4];   // [jt][ks]
  #pragma unroll
  for (int jt = 0; jt < 4; ++jt)
    #pragma unroll
    for (int ks = 0; ks < 4; ++ks)
      kf[jt][ks] = *(const short8*)(Kb + (size_t)(jt * 16 + li) * NE + ks * 32 + g * 8);

  #pragma unroll 1
  for (int it = 0; it < NIT; ++it) {
    const int j0 = it * KVB;

    // ---- issue all V loads for this iter (consumed after softmax) ----
    short8 vf[8][2];
    #pragma unroll
    for (int et = 0; et < 8; ++et) {
      const unsigned short* Vrow = VTb + (size_t)(et * 16 + li) * NS + j0 + g * 8;
      vf[et][0] = *(const short8*)(Vrow);
      vf[et][1] = *(const short8*)(Vrow + 32);
    }

    // ---- QK from resident K regs (counted vmcnt: V stays in flight) ----
    f32x4 s[4];
    #pragma unroll
    for (int jt = 0; jt < 4; ++jt) {
      s[jt] = (f32x4){0.f, 0.f, 0.f, 0.f};
      #pragma unroll
      for (int ks = 0; ks < 4; ++ks)
        s[jt] = __builtin_amdgcn_mfma_f32_16x16x32_bf16(kf[jt][ks], qf[ks], s[jt], 0, 0, 0);
    }

    // ---- prefetch next iter's K tile (wraps on last iter; data unused) ----
    const int jn = ((it + 1) & (NIT - 1)) * KVB;
    #pragma unroll
    for (int jt = 0; jt < 4; ++jt)
      #pragma unroll
      for (int ks = 0; ks < 4; ++ks)
        kf[jt][ks] = *(const short8*)(Kb + (size_t)(jn + jt * 16 + li) * NE + ks * 32 + g * 8);

    // ---- fresh-max online softmax (row i per lane, replicated over g) ----
    float tm = fmaxf(fmaxf(fmaxf(s[0][0], s[0][1]), fmaxf(s[0][2], s[0][3])),
                     fmaxf(fmaxf(s[1][0], s[1][1]), fmaxf(s[1][2], s[1][3])));
    tm = fmaxf(tm, fmaxf(fmaxf(fmaxf(s[2][0], s[2][1]), fmaxf(s[2][2], s[2][3])),
                         fmaxf(fmaxf(s[3][0], s[3][1]), fmaxf(s[3][2], s[3][3]))));
    tm = fmaxf(tm, __shfl_xor(tm, 16));
    tm = fmaxf(tm, __shfl_xor(tm, 32));
    float mn = fmaxf(m2, tm);
    float c  = __builtin_amdgcn_exp2f(m2 - mn);
    #pragma unroll
    for (int et = 0; et < 8; ++et) o[et] = o[et] * c;
    m2 = mn;

    // ---- P = exp2(S - m2) <= 1, pack to bf16 pairs (manual RNE) ----
    unsigned int pk[4][2];
    float ts = 0.f;
    #pragma unroll
    for (int jt = 0; jt < 4; ++jt) {
      float p0 = __builtin_amdgcn_exp2f(s[jt][0] - m2);
      float p1 = __builtin_amdgcn_exp2f(s[jt][1] - m2);
      float p2 = __builtin_amdgcn_exp2f(s[jt][2] - m2);
      float p3 = __builtin_amdgcn_exp2f(s[jt][3] - m2);
      ts += (p0 + p1) + (p2 + p3);
      pk[jt][0] = (unsigned int)f2bf(p0) | ((unsigned int)f2bf(p1) << 16);
      pk[jt][1] = (unsigned int)f2bf(p2) | ((unsigned int)f2bf(p3) << 16);
    }
    Lp = Lp * c + ts;

    // ---- redistribute P into two PV B-frags (16 shfl + 8 sel) ----
    int ta, tb, w0, w1, w2, w3;
    union { int4v i4; short8 s8; } pb0, pb1;
    ta = __shfl((int)pk[0][0], l0); tb = __shfl((int)pk[1][0], l0); w0 = (g < 2) ? ta : tb;
    ta = __shfl((int)pk[0][1], l0); tb = __shfl((int)pk[1][1], l0); w1 = (g < 2) ? ta : tb;
    ta = __shfl((int)pk[0][0], l1); tb = __shfl((int)pk[1][0], l1); w2 = (g < 2) ? ta : tb;
    ta = __shfl((int)pk[0][1], l1); tb = __shfl((int)pk[1][1], l1); w3 = (g < 2) ? ta : tb;
    pb0.i4 = (int4v){w0, w1, w2, w3};
    ta = __shfl((int)pk[2][0], l0); tb = __shfl((int)pk[3][0], l0); w0 = (g < 2) ? ta : tb;
    ta = __shfl((int)pk[2][1], l0); tb = __shfl((int)pk[3][1], l0); w1 = (g < 2) ? ta : tb;
    ta = __shfl((int)pk[2][0], l1); tb = __shfl((int)pk[3][0], l1); w2 = (g < 2) ? ta : tb;
    ta = __shfl((int)pk[2][1], l1); tb = __shfl((int)pk[3][1], l1); w3 = (g < 2) ? ta : tb;
    pb1.i4 = (int4v){w0, w1, w2, w3};

    // ---- PV: O^T += VT(:, j0..j0+63) @ P^T ----
    #pragma unroll
    for (int et = 0; et < 8; ++et) {
      o[et] = __builtin_amdgcn_mfma_f32_16x16x32_bf16(vf[et][0], pb0.s8, o[et], 0, 0, 0);
      o[et] = __builtin_amdgcn_mfma_f32_16x16x32_bf16(vf[et][1], pb1.s8, o[et], 0, 0, 0);
    }
  }

  // ---- epilogue: publish partials to LDS ----
  Lp += __shfl_xor(Lp, 16);
  Lp += __shfl_xor(Lp, 32);          // row-sum, replicated across g
  #pragma unroll
  for (int et = 0; et < 8; ++et) {
    float4 v; v.x = o[et][0]; v.y = o[et][1]; v.z = o[et][2]; v.w = o[et][3];
    smO[qtw][sp][et][lane] = v;
  }
  if (lane < 16) {
    smML[qtw][sp][0][lane] = m2;
    smML[qtw][sp][1][lane] = Lp;
  }
  __syncthreads();

  // ---- combine: wave wv handles q-tile (wv>>2), et pair (wv&3)*2 ----
  const int cqt  = wv >> 2;
  const int cet0 = (wv & 3) * 2;
  float ms[SPLITS], Ls[SPLITS];
  #pragma unroll
  for (int s2 = 0; s2 < SPLITS; ++s2) {
    ms[s2] = smML[cqt][s2][0][li];
    Ls[s2] = smML[cqt][s2][1][li];
  }
  float M = fmaxf(fmaxf(ms[0], ms[1]), fmaxf(ms[2], ms[3]));
  float W[SPLITS], Ltot = 0.f;
  #pragma unroll
  for (int s2 = 0; s2 < SPLITS; ++s2) {
    W[s2] = __builtin_amdgcn_exp2f(ms[s2] - M);
    Ltot += W[s2] * Ls[s2];
  }
  const float rL = 1.f / Ltot;
  const int orow = b * NS + (within * 2 + cqt) * 16 + li;
  #pragma unroll
  for (int e2 = 0; e2 < 2; ++e2) {
    const int et = cet0 + e2;
    float4 acc = make_float4(0.f, 0.f, 0.f, 0.f);
    #pragma unroll
    for (int s2 = 0; s2 < SPLITS; ++s2) {
      float4 v = smO[cqt][s2][et][lane];
      acc.x += W[s2] * v.x; acc.y += W[s2] * v.y;
      acc.z += W[s2] * v.z; acc.w += W[s2] * v.w;
    }
    acc.x *= rL; acc.y *= rL; acc.z *= rL; acc.w *= rL;
    *(float4*)(Out + (size_t)orow * NE + et * 16 + g * 4) = acc;
  }
}

extern "C" void kernel_launch(void* const* d_in, const int* in_sizes, int n_in,
                              void* d_out, int out_size, void* d_ws, size_t ws_size,
                              hipStream_t stream) {
  const float* X  = (const float*)d_in[0];
  // d_in[1] = context : unused (per-row bias is softmax-invariant)
  const float* Wq = (const float*)d_in[2];
  const float* bq = (const float*)d_in[3];
  const float* Wk = (const float*)d_in[4];
  const float* bk = (const float*)d_in[5];
  const float* Wv = (const float*)d_in[6];
  const float* bv = (const float*)d_in[7];
  // d_in[8] = Wc, d_in[9] = bc : unused

  unsigned short* Qs  = (unsigned short*)d_ws;                // 4 MB
  unsigned short* Kd  = Qs + (size_t)NB * NS * NE;            // 4 MB
  unsigned short* VT  = Kd + (size_t)NB * NS * NE;            // 4 MB
  unsigned short* Wqb = VT + (size_t)NB * NS * NE;            // 32 KB x3
  unsigned short* Wkb = Wqb + NE * NE;
  unsigned short* Wvb = Wkb + NE * NE;

  prep_k<<<48, 256, 0, stream>>>(Wq, Wk, Wv, Wqb, Wkb, Wvb);
  qkv_proj_k<<<512, 256, 0, stream>>>(X, Wqb, bq, Wkb, bk, Wvb, bv, Qs, Kd, VT);
  attn_k<<<512, 512, 0, stream>>>(Qs, Kd, VT, (float*)d_out);
}

// Round 6
// 163.952 us; speedup vs baseline: 1.7479x; 1.5824x over previous
//
#include <hip/hip_runtime.h>
#include <hip/hip_bf16.h>

typedef short short8 __attribute__((ext_vector_type(8)));
typedef float f32x4 __attribute__((ext_vector_type(4)));
typedef int int4v __attribute__((ext_vector_type(4)));
typedef unsigned short ushort4v __attribute__((ext_vector_type(4)));

#define NB 4
#define NS 4096
#define NE 128
#define ALPHA 0.1275174468f  /* log2(e)/sqrt(128) */
#define KVB 64                 /* keys per inner iteration */
#define NIT (NS / KVB)         /* 64 */

static __device__ __forceinline__ unsigned short f2bf(float f) {
  union { float f; unsigned int u; } v; v.f = f;
  unsigned int u = v.u;
  return (unsigned short)((u + 0x7FFFu + ((u >> 16) & 1u)) >> 16);
}

static __device__ __forceinline__ void gload_lds16(const unsigned short* g,
                                                   unsigned short* l) {
  __builtin_amdgcn_global_load_lds(
      (const __attribute__((address_space(1))) unsigned int*)g,
      (__attribute__((address_space(3))) unsigned int*)l, 16, 0, 0);
}

// ---------------------------------------------------------------------------
// Kernel 0: one-time f32 -> bf16 conversion of the three weight matrices.
// ---------------------------------------------------------------------------
__global__ __launch_bounds__(256) void prep_k(
    const float* __restrict__ Wq, const float* __restrict__ Wk,
    const float* __restrict__ Wv,
    unsigned short* __restrict__ Wqb, unsigned short* __restrict__ Wkb,
    unsigned short* __restrict__ Wvb) {
  int i = blockIdx.x * 256 + threadIdx.x;          // 0..12287
  const float* srcs[3] = {Wq, Wk, Wv};
  unsigned short* dsts[3] = {Wqb, Wkb, Wvb};
  int m = i >> 12, off = (i & 4095) * 4;
  float4 v = *(const float4*)(srcs[m] + off);
  ushort4v o;
  o[0] = f2bf(v.x); o[1] = f2bf(v.y); o[2] = f2bf(v.z); o[3] = f2bf(v.w);
  *(ushort4v*)(dsts[m] + off) = o;
}

static __device__ __forceinline__ f32x4 wtile(const short8 xa[4],
                                              const unsigned short* __restrict__ Wb,
                                              int fb, int g, int li) {
  f32x4 acc = {0.f, 0.f, 0.f, 0.f};
  #pragma unroll
  for (int ks = 0; ks < 4; ++ks) {
    short8 wf = *(const short8*)(Wb + (fb * 16 + li) * NE + ks * 32 + g * 8);
    acc = __builtin_amdgcn_mfma_f32_16x16x32_bf16(xa[ks], wf, acc, 0, 0, 0);
  }
  return acc;
}

// ---------------------------------------------------------------------------
// Kernel 1: fused QKV projection (f32 in, bf16 staged out).
// ---------------------------------------------------------------------------
__global__ __launch_bounds__(256) void qkv_proj_k(
    const float* __restrict__ X,
    const unsigned short* __restrict__ Wqb, const float* __restrict__ bq,
    const unsigned short* __restrict__ Wkb, const float* __restrict__ bk,
    const unsigned short* __restrict__ Wvb, const float* __restrict__ bv,
    unsigned short* __restrict__ Qs, unsigned short* __restrict__ Kd,
    unsigned short* __restrict__ VT) {
  const int lane = threadIdx.x & 63;
  const int wv   = threadIdx.x >> 6;
  const int tile = (blockIdx.x >> 1) * 4 + wv;   // 0..1023
  const int fb0  = (blockIdx.x & 1) * 4;         // output half
  const int m0   = tile * 16;
  const int g    = lane >> 4, li = lane & 15;

  short8 xa[4];
  #pragma unroll
  for (int ks = 0; ks < 4; ++ks) {
    const float* xp = X + (size_t)(m0 + li) * NE + ks * 32 + g * 8;
    float4 x0 = *(const float4*)xp;
    float4 x1 = *(const float4*)(xp + 4);
    short8 t;
    t[0] = (short)f2bf(x0.x); t[1] = (short)f2bf(x0.y);
    t[2] = (short)f2bf(x0.z); t[3] = (short)f2bf(x0.w);
    t[4] = (short)f2bf(x1.x); t[5] = (short)f2bf(x1.y);
    t[6] = (short)f2bf(x1.z); t[7] = (short)f2bf(x1.w);
    xa[ks] = t;
  }

  const int bb = m0 >> 12;
  const int n0 = (m0 & 4095) + g * 4;

  #pragma unroll
  for (int f2 = 0; f2 < 4; ++f2) {
    const int fb = fb0 + f2;
    f32x4 aq = wtile(xa, Wqb, fb, g, li);
    float biq = bq[fb * 16 + li];
    #pragma unroll
    for (int r = 0; r < 4; ++r)
      Qs[(size_t)(m0 + g * 4 + r) * NE + fb * 16 + li] = f2bf((aq[r] + biq) * ALPHA);
    f32x4 ak = wtile(xa, Wkb, fb, g, li);
    float bik = bk[fb * 16 + li];
    #pragma unroll
    for (int r = 0; r < 4; ++r)
      Kd[(size_t)(m0 + g * 4 + r) * NE + fb * 16 + li] = f2bf(ak[r] + bik);
    f32x4 av = wtile(xa, Wvb, fb, g, li);
    float biv = bv[fb * 16 + li];
    ushort4v pv;
    #pragma unroll
    for (int r = 0; r < 4; ++r) pv[r] = f2bf(av[r] + biv);
    *(ushort4v*)(VT + (size_t)bb * (NE * NS) + (size_t)(fb * 16 + li) * NS + n0) = pv;
  }
}

// ---------------------------------------------------------------------------
// Kernel 2: flash attention, LDS-staged double-buffered K/V (2-phase).
// 256 threads = 4 waves = 4 q-tiles (64 q-rows), full key sweep.
// Per 64-key tile: K+V (32 KB) staged once per block via global_load_lds,
// all 4 waves consume from LDS. LDS layout = [group][lane] 16B chunks
// (lane-linear dest; per-lane global source) -> conflict-free ds_read_b128.
// ---------------------------------------------------------------------------
__global__ __launch_bounds__(256, 2) void attn_k(
    const unsigned short* __restrict__ Qs, const unsigned short* __restrict__ Kd,
    const unsigned short* __restrict__ VT, float* __restrict__ Out) {
  __shared__ unsigned short kbuf[2][KVB * NE];   // 2 x 16 KB
  __shared__ unsigned short vbuf[2][NE * KVB];   // 2 x 16 KB

  const int lane = threadIdx.x & 63;
  const int wv   = threadIdx.x >> 6;             // 0..3
  const int bi   = blockIdx.x;                   // 0..255
  const int b    = (bi >> 1) & 3;                // batch tied to XCD pair
  const int within = ((bi >> 3) << 1) | (bi & 1);     // 0..63
  const int qb   = (within * 4 + wv) * 16;       // q-row tile base
  const int g    = lane >> 4, li = lane & 15;

  // Q B-frags: B[k=e][col=i=li]
  const unsigned short* Qrow = Qs + (size_t)(b * NS + qb + li) * NE + g * 8;
  short8 qf[4];
  #pragma unroll
  for (int ks = 0; ks < 4; ++ks) qf[ks] = *(const short8*)(Qrow + ks * 32);

  const unsigned short* Kb  = Kd + (size_t)b * (NS * NE);
  const unsigned short* VTb = VT + (size_t)b * (NE * NS);

  f32x4 o[8];
  #pragma unroll
  for (int et = 0; et < 8; ++et) o[et] = (f32x4){0.f, 0.f, 0.f, 0.f};
  float m2 = -1e30f, Lp = 0.f;

  const int l0 = ((g & 1) << 5) + li;
  const int l1 = l0 + 16;

  // stage: wave wv handles K groups (jt=wv, ks=0..3) and V groups
  // gidx2 = wv*4+i (et=gidx2>>1, h=gidx2&1). 1 KB per instruction.
  #define STAGE(BUF, J0)                                                        \
    {                                                                           \
      _Pragma("unroll")                                                         \
      for (int i_ = 0; i_ < 4; ++i_) {                                          \
        gload_lds16(Kb + (size_t)((J0) + wv * 16 + li) * NE + i_ * 32 + g * 8,  \
                    &kbuf[BUF][(wv * 4 + i_) * 512]);                           \
      }                                                                         \
      _Pragma("unroll")                                                         \
      for (int i_ = 0; i_ < 4; ++i_) {                                          \
        const int et_ = (wv * 4 + i_) >> 1, h_ = (wv * 4 + i_) & 1;             \
        gload_lds16(VTb + (size_t)(et_ * 16 + li) * NS + (J0) + h_ * 32 + g * 8,\
                    &vbuf[BUF][(wv * 4 + i_) * 512]);                           \
      }                                                                         \
    }

  STAGE(0, 0);
  asm volatile("s_waitcnt vmcnt(0)" ::: "memory");
  __syncthreads();

  #pragma unroll 1
  for (int t = 0; t < NIT; ++t) {
    const int curb = t & 1;
    if (t + 1 < NIT) STAGE(curb ^ 1, (t + 1) * KVB);

    // ---- QK from LDS: group (jt,ks) at [(jt*4+ks)*512 + lane*8] shorts ----
    f32x4 s[4];
    #pragma unroll
    for (int jt = 0; jt < 4; ++jt) {
      s[jt] = (f32x4){0.f, 0.f, 0.f, 0.f};
      #pragma unroll
      for (int ks = 0; ks < 4; ++ks) {
        short8 kfr = *(const short8*)(&kbuf[curb][(jt * 4 + ks) * 512 + lane * 8]);
        s[jt] = __builtin_amdgcn_mfma_f32_16x16x32_bf16(kfr, qf[ks], s[jt], 0, 0, 0);
      }
    }

    // ---- fresh-max online softmax (row i per lane, replicated over g) ----
    float tm = fmaxf(fmaxf(fmaxf(s[0][0], s[0][1]), fmaxf(s[0][2], s[0][3])),
                     fmaxf(fmaxf(s[1][0], s[1][1]), fmaxf(s[1][2], s[1][3])));
    tm = fmaxf(tm, fmaxf(fmaxf(fmaxf(s[2][0], s[2][1]), fmaxf(s[2][2], s[2][3])),
                         fmaxf(fmaxf(s[3][0], s[3][1]), fmaxf(s[3][2], s[3][3]))));
    tm = fmaxf(tm, __shfl_xor(tm, 16));
    tm = fmaxf(tm, __shfl_xor(tm, 32));
    float mn = fmaxf(m2, tm);
    float c  = __builtin_amdgcn_exp2f(m2 - mn);
    #pragma unroll
    for (int et = 0; et < 8; ++et) o[et] = o[et] * c;
    m2 = mn;

    // ---- P = exp2(S - m2) <= 1, pack to bf16 pairs (manual RNE) ----
    unsigned int pk[4][2];
    float ts = 0.f;
    #pragma unroll
    for (int jt = 0; jt < 4; ++jt) {
      float p0 = __builtin_amdgcn_exp2f(s[jt][0] - m2);
      float p1 = __builtin_amdgcn_exp2f(s[jt][1] - m2);
      float p2 = __builtin_amdgcn_exp2f(s[jt][2] - m2);
      float p3 = __builtin_amdgcn_exp2f(s[jt][3] - m2);
      ts += (p0 + p1) + (p2 + p3);
      pk[jt][0] = (unsigned int)f2bf(p0) | ((unsigned int)f2bf(p1) << 16);
      pk[jt][1] = (unsigned int)f2bf(p2) | ((unsigned int)f2bf(p3) << 16);
    }
    Lp = Lp * c + ts;

    // ---- redistribute P into two PV B-frags (16 shfl + 8 sel) ----
    int ta, tb, w0, w1, w2, w3;
    union { int4v i4; short8 s8; } pb0, pb1;
    ta = __shfl((int)pk[0][0], l0); tb = __shfl((int)pk[1][0], l0); w0 = (g < 2) ? ta : tb;
    ta = __shfl((int)pk[0][1], l0); tb = __shfl((int)pk[1][1], l0); w1 = (g < 2) ? ta : tb;
    ta = __shfl((int)pk[0][0], l1); tb = __shfl((int)pk[1][0], l1); w2 = (g < 2) ? ta : tb;
    ta = __shfl((int)pk[0][1], l1); tb = __shfl((int)pk[1][1], l1); w3 = (g < 2) ? ta : tb;
    pb0.i4 = (int4v){w0, w1, w2, w3};
    ta = __shfl((int)pk[2][0], l0); tb = __shfl((int)pk[3][0], l0); w0 = (g < 2) ? ta : tb;
    ta = __shfl((int)pk[2][1], l0); tb = __shfl((int)pk[3][1], l0); w1 = (g < 2) ? ta : tb;
    ta = __shfl((int)pk[2][0], l1); tb = __shfl((int)pk[3][0], l1); w2 = (g < 2) ? ta : tb;
    ta = __shfl((int)pk[2][1], l1); tb = __shfl((int)pk[3][1], l1); w3 = (g < 2) ? ta : tb;
    pb1.i4 = (int4v){w0, w1, w2, w3};

    // ---- PV from LDS: group (et,h) at [(et*2+h)*512 + lane*8] shorts ----
    #pragma unroll
    for (int et = 0; et < 8; ++et) {
      short8 vf0 = *(const short8*)(&vbuf[curb][(et * 2 + 0) * 512 + lane * 8]);
      o[et] = __builtin_amdgcn_mfma_f32_16x16x32_bf16(vf0, pb0.s8, o[et], 0, 0, 0);
      short8 vf1 = *(const short8*)(&vbuf[curb][(et * 2 + 1) * 512 + lane * 8]);
      o[et] = __builtin_amdgcn_mfma_f32_16x16x32_bf16(vf1, pb1.s8, o[et], 0, 0, 0);
    }

    __syncthreads();   // drains own vmcnt/lgkmcnt, then barrier
  }

  // ---- epilogue: reduce L across g-replicas, store O[b, qb+li, e] as f32 ----
  Lp += __shfl_xor(Lp, 16);
  Lp += __shfl_xor(Lp, 32);
  const float rL = 1.f / Lp;
  float* Orow = Out + (size_t)(b * NS + qb + li) * NE;
  #pragma unroll
  for (int et = 0; et < 8; ++et) {
    float4 v;
    v.x = o[et][0] * rL; v.y = o[et][1] * rL;
    v.z = o[et][2] * rL; v.w = o[et][3] * rL;
    *(float4*)(Orow + et * 16 + g * 4) = v;
  }
}

extern "C" void kernel_launch(void* const* d_in, const int* in_sizes, int n_in,
                              void* d_out, int out_size, void* d_ws, size_t ws_size,
                              hipStream_t stream) {
  const float* X  = (const float*)d_in[0];
  // d_in[1] = context : unused (per-row bias is softmax-invariant)
  const float* Wq = (const float*)d_in[2];
  const float* bq = (const float*)d_in[3];
  const float* Wk = (const float*)d_in[4];
  const float* bk = (const float*)d_in[5];
  const float* Wv = (const float*)d_in[6];
  const float* bv = (const float*)d_in[7];
  // d_in[8] = Wc, d_in[9] = bc : unused

  unsigned short* Qs  = (unsigned short*)d_ws;                // 4 MB
  unsigned short* Kd  = Qs + (size_t)NB * NS * NE;            // 4 MB
  unsigned short* VT  = Kd + (size_t)NB * NS * NE;            // 4 MB
  unsigned short* Wqb = VT + (size_t)NB * NS * NE;            // 32 KB x3
  unsigned short* Wkb = Wqb + NE * NE;
  unsigned short* Wvb = Wkb + NE * NE;

  prep_k<<<48, 256, 0, stream>>>(Wq, Wk, Wv, Wqb, Wkb, Wvb);
  qkv_proj_k<<<512, 256, 0, stream>>>(X, Wqb, bq, Wkb, bk, Wvb, bv, Qs, Kd, VT);
  attn_k<<<256, 256, 0, stream>>>(Qs, Kd, VT, (float*)d_out);
}

// Round 7
// 146.941 us; speedup vs baseline: 1.9503x; 1.1158x over previous
//
#include <hip/hip_runtime.h>
#include <hip/hip_bf16.h>

typedef short short8 __attribute__((ext_vector_type(8)));
typedef float f32x4 __attribute__((ext_vector_type(4)));
typedef int int4v __attribute__((ext_vector_type(4)));
typedef unsigned short ushort4v __attribute__((ext_vector_type(4)));

#define NB 4
#define NS 4096
#define NE 128
#define ALPHA 0.1275174468f  /* log2(e)/sqrt(128) */
#define KVB 64                 /* keys per staged tile */
#define NIT (NS / KVB)         /* 64 */
#define SPLITS 2               /* j-half splits sharing one staged tile */

static __device__ __forceinline__ unsigned short f2bf(float f) {
  union { float f; unsigned int u; } v; v.f = f;
  unsigned int u = v.u;
  return (unsigned short)((u + 0x7FFFu + ((u >> 16) & 1u)) >> 16);
}

static __device__ __forceinline__ void gload_lds16(const unsigned short* g,
                                                   unsigned short* l) {
  __builtin_amdgcn_global_load_lds(
      (const __attribute__((address_space(1))) unsigned int*)g,
      (__attribute__((address_space(3))) unsigned int*)l, 16, 0, 0);
}

// ---------------------------------------------------------------------------
// Kernel 0: one-time f32 -> bf16 conversion of the three weight matrices.
// ---------------------------------------------------------------------------
__global__ __launch_bounds__(256) void prep_k(
    const float* __restrict__ Wq, const float* __restrict__ Wk,
    const float* __restrict__ Wv,
    unsigned short* __restrict__ Wqb, unsigned short* __restrict__ Wkb,
    unsigned short* __restrict__ Wvb) {
  int i = blockIdx.x * 256 + threadIdx.x;          // 0..12287
  const float* srcs[3] = {Wq, Wk, Wv};
  unsigned short* dsts[3] = {Wqb, Wkb, Wvb};
  int m = i >> 12, off = (i & 4095) * 4;
  float4 v = *(const float4*)(srcs[m] + off);
  ushort4v o;
  o[0] = f2bf(v.x); o[1] = f2bf(v.y); o[2] = f2bf(v.z); o[3] = f2bf(v.w);
  *(ushort4v*)(dsts[m] + off) = o;
}

static __device__ __forceinline__ f32x4 wtile(const short8 xa[4],
                                              const unsigned short* __restrict__ Wb,
                                              int fb, int g, int li) {
  f32x4 acc = {0.f, 0.f, 0.f, 0.f};
  #pragma unroll
  for (int ks = 0; ks < 4; ++ks) {
    short8 wf = *(const short8*)(Wb + (fb * 16 + li) * NE + ks * 32 + g * 8);
    acc = __builtin_amdgcn_mfma_f32_16x16x32_bf16(xa[ks], wf, acc, 0, 0, 0);
  }
  return acc;
}

// ---------------------------------------------------------------------------
// Kernel 1: fused QKV projection (f32 in, bf16 staged out).
// ---------------------------------------------------------------------------
__global__ __launch_bounds__(256) void qkv_proj_k(
    const float* __restrict__ X,
    const unsigned short* __restrict__ Wqb, const float* __restrict__ bq,
    const unsigned short* __restrict__ Wkb, const float* __restrict__ bk,
    const unsigned short* __restrict__ Wvb, const float* __restrict__ bv,
    unsigned short* __restrict__ Qs, unsigned short* __restrict__ Kd,
    unsigned short* __restrict__ VT) {
  const int lane = threadIdx.x & 63;
  const int wv   = threadIdx.x >> 6;
  const int tile = (blockIdx.x >> 1) * 4 + wv;   // 0..1023
  const int fb0  = (blockIdx.x & 1) * 4;         // output half
  const int m0   = tile * 16;
  const int g    = lane >> 4, li = lane & 15;

  short8 xa[4];
  #pragma unroll
  for (int ks = 0; ks < 4; ++ks) {
    const float* xp = X + (size_t)(m0 + li) * NE + ks * 32 + g * 8;
    float4 x0 = *(const float4*)xp;
    float4 x1 = *(const float4*)(xp + 4);
    short8 t;
    t[0] = (short)f2bf(x0.x); t[1] = (short)f2bf(x0.y);
    t[2] = (short)f2bf(x0.z); t[3] = (short)f2bf(x0.w);
    t[4] = (short)f2bf(x1.x); t[5] = (short)f2bf(x1.y);
    t[6] = (short)f2bf(x1.z); t[7] = (short)f2bf(x1.w);
    xa[ks] = t;
  }

  const int bb = m0 >> 12;
  const int n0 = (m0 & 4095) + g * 4;

  #pragma unroll
  for (int f2 = 0; f2 < 4; ++f2) {
    const int fb = fb0 + f2;
    f32x4 aq = wtile(xa, Wqb, fb, g, li);
    float biq = bq[fb * 16 + li];
    #pragma unroll
    for (int r = 0; r < 4; ++r)
      Qs[(size_t)(m0 + g * 4 + r) * NE + fb * 16 + li] = f2bf((aq[r] + biq) * ALPHA);
    f32x4 ak = wtile(xa, Wkb, fb, g, li);
    float bik = bk[fb * 16 + li];
    #pragma unroll
    for (int r = 0; r < 4; ++r)
      Kd[(size_t)(m0 + g * 4 + r) * NE + fb * 16 + li] = f2bf(ak[r] + bik);
    f32x4 av = wtile(xa, Wvb, fb, g, li);
    float biv = bv[fb * 16 + li];
    ushort4v pv;
    #pragma unroll
    for (int r = 0; r < 4; ++r) pv[r] = f2bf(av[r] + biv);
    *(ushort4v*)(VT + (size_t)bb * (NE * NS) + (size_t)(fb * 16 + li) * NS + n0) = pv;
  }
}

// ---------------------------------------------------------------------------
// Kernel 2: flash attention, LDS-staged double-buffered K/V, in-tile split-K.
// 512 blocks x 256 threads (4 waves) = 2 blocks/CU, 8 waves/CU.
// Block = 2 q-tiles x 2 j-half-splits; both splits consume the SAME staged
// 64-key tile (wave sp takes j-subtiles sp*2, sp*2+1 as an independent
// online-softmax split). In-LDS combine at the end (SPLITS=2).
// ---------------------------------------------------------------------------
__global__ __launch_bounds__(256, 2) void attn_k(
    const unsigned short* __restrict__ Qs, const unsigned short* __restrict__ Kd,
    const unsigned short* __restrict__ VT, float* __restrict__ Out) {
  __shared__ __align__(16) unsigned char lds_raw[66560];
  unsigned short* kb_lds = (unsigned short*)lds_raw;           // [2][8192]
  unsigned short* vb_lds = (unsigned short*)(lds_raw + 32768); // [2][8192]
  float*          smML   = (float*)(lds_raw + 65536);          // [2][2][2][16]
  float4*         smO    = (float4*)lds_raw;                   // [2][2][8][64] (epilogue alias)

  const int lane = threadIdx.x & 63;
  const int wv   = threadIdx.x >> 6;             // 0..3
  const int qtw  = wv >> 1;                      // q-tile within block (0..1)
  const int sp   = wv & 1;                       // j-half split (0..1)
  const int bi   = blockIdx.x;                   // 0..511
  const int b    = (bi >> 1) & 3;                // batch tied to XCD pair
  const int within = ((bi >> 3) << 1) | (bi & 1);     // 0..127
  const int qb   = (within * 2 + qtw) * 16;      // q-row tile base
  const int g    = lane >> 4, li = lane & 15;

  // Q B-frags: B[k=e][col=i=li]
  const unsigned short* Qrow = Qs + (size_t)(b * NS + qb + li) * NE + g * 8;
  short8 qf[4];
  #pragma unroll
  for (int ks = 0; ks < 4; ++ks) qf[ks] = *(const short8*)(Qrow + ks * 32);

  const unsigned short* Kb  = Kd + (size_t)b * (NS * NE);
  const unsigned short* VTb = VT + (size_t)b * (NE * NS);

  f32x4 o[8];
  #pragma unroll
  for (int et = 0; et < 8; ++et) o[et] = (f32x4){0.f, 0.f, 0.f, 0.f};
  float m2 = -1e30f, Lp = 0.f;

  const int l0 = ((g & 1) << 5) + li;
  const int l1 = l0 + 16;

  // staging partition: wave wv loads K groups (jt=wv, ks=0..3) and V groups
  // gidx=wv*4+i (et=gidx>>1, h=gidx&1). 1 KB per instruction, lane-linear dest.
  #define STAGE(BUF, J0)                                                        \
    {                                                                           \
      _Pragma("unroll")                                                         \
      for (int i_ = 0; i_ < 4; ++i_) {                                          \
        gload_lds16(Kb + (size_t)((J0) + wv * 16 + li) * NE + i_ * 32 + g * 8,  \
                    kb_lds + (BUF) * 8192 + (wv * 4 + i_) * 512);               \
      }                                                                         \
      _Pragma("unroll")                                                         \
      for (int i_ = 0; i_ < 4; ++i_) {                                          \
        const int et_ = (wv * 4 + i_) >> 1, h_ = (wv * 4 + i_) & 1;             \
        gload_lds16(VTb + (size_t)(et_ * 16 + li) * NS + (J0) + h_ * 32 + g * 8,\
                    vb_lds + (BUF) * 8192 + (wv * 4 + i_) * 512);               \
      }                                                                         \
    }

  STAGE(0, 0);
  asm volatile("s_waitcnt vmcnt(0)" ::: "memory");
  __syncthreads();

  #pragma unroll 1
  for (int t = 0; t < NIT; ++t) {
    const int curb = t & 1;
    if (t + 1 < NIT) STAGE(curb ^ 1, (t + 1) * KVB);

    // ---- QK for own j-half: subtiles jt = sp*2 + {0,1} ----
    f32x4 s[2];
    __builtin_amdgcn_s_setprio(1);
    #pragma unroll
    for (int jh = 0; jh < 2; ++jh) {
      const int jt = sp * 2 + jh;
      s[jh] = (f32x4){0.f, 0.f, 0.f, 0.f};
      #pragma unroll
      for (int ks = 0; ks < 4; ++ks) {
        short8 kfr = *(const short8*)(kb_lds + curb * 8192 + (jt * 4 + ks) * 512 + lane * 8);
        s[jh] = __builtin_amdgcn_mfma_f32_16x16x32_bf16(kfr, qf[ks], s[jh], 0, 0, 0);
      }
    }
    __builtin_amdgcn_s_setprio(0);

    // ---- fresh-max online softmax over this wave's 32 keys ----
    float tm = fmaxf(fmaxf(fmaxf(s[0][0], s[0][1]), fmaxf(s[0][2], s[0][3])),
                     fmaxf(fmaxf(s[1][0], s[1][1]), fmaxf(s[1][2], s[1][3])));
    tm = fmaxf(tm, __shfl_xor(tm, 16));
    tm = fmaxf(tm, __shfl_xor(tm, 32));
    float mn = fmaxf(m2, tm);
    float c  = __builtin_amdgcn_exp2f(m2 - mn);
    #pragma unroll
    for (int et = 0; et < 8; ++et) o[et] = o[et] * c;
    m2 = mn;

    // ---- P = exp2(S - m2) <= 1, pack to bf16 pairs (manual RNE) ----
    unsigned int pk[2][2];
    float ts = 0.f;
    #pragma unroll
    for (int jh = 0; jh < 2; ++jh) {
      float p0 = __builtin_amdgcn_exp2f(s[jh][0] - m2);
      float p1 = __builtin_amdgcn_exp2f(s[jh][1] - m2);
      float p2 = __builtin_amdgcn_exp2f(s[jh][2] - m2);
      float p3 = __builtin_amdgcn_exp2f(s[jh][3] - m2);
      ts += (p0 + p1) + (p2 + p3);
      pk[jh][0] = (unsigned int)f2bf(p0) | ((unsigned int)f2bf(p1) << 16);
      pk[jh][1] = (unsigned int)f2bf(p2) | ((unsigned int)f2bf(p3) << 16);
    }
    Lp = Lp * c + ts;

    // ---- redistribute P into one PV B-frag (8 shfl + 4 sel) ----
    int ta, tb, w0, w1, w2, w3;
    union { int4v i4; short8 s8; } pb;
    ta = __shfl((int)pk[0][0], l0); tb = __shfl((int)pk[1][0], l0); w0 = (g < 2) ? ta : tb;
    ta = __shfl((int)pk[0][1], l0); tb = __shfl((int)pk[1][1], l0); w1 = (g < 2) ? ta : tb;
    ta = __shfl((int)pk[0][0], l1); tb = __shfl((int)pk[1][0], l1); w2 = (g < 2) ? ta : tb;
    ta = __shfl((int)pk[0][1], l1); tb = __shfl((int)pk[1][1], l1); w3 = (g < 2) ? ta : tb;
    pb.i4 = (int4v){w0, w1, w2, w3};

    // ---- PV over own 32-key half: V group (et*2 + sp) ----
    __builtin_amdgcn_s_setprio(1);
    #pragma unroll
    for (int et = 0; et < 8; ++et) {
      short8 vfr = *(const short8*)(vb_lds + curb * 8192 + (et * 2 + sp) * 512 + lane * 8);
      o[et] = __builtin_amdgcn_mfma_f32_16x16x32_bf16(vfr, pb.s8, o[et], 0, 0, 0);
    }
    __builtin_amdgcn_s_setprio(0);

    __syncthreads();   // drains own vmcnt/lgkmcnt, then barrier
  }

  // ---- epilogue: publish split partials (smO aliases staging region) ----
  Lp += __shfl_xor(Lp, 16);
  Lp += __shfl_xor(Lp, 32);          // row-sum, replicated across g
  #pragma unroll
  for (int et = 0; et < 8; ++et) {
    float4 v; v.x = o[et][0]; v.y = o[et][1]; v.z = o[et][2]; v.w = o[et][3];
    smO[((qtw * 2 + sp) * 8 + et) * 64 + lane] = v;
  }
  if (lane < 16) {
    smML[((qtw * 2 + sp) * 2 + 0) * 16 + lane] = m2;
    smML[((qtw * 2 + sp) * 2 + 1) * 16 + lane] = Lp;
  }
  __syncthreads();

  // ---- combine: wave wv handles q-tile (wv>>1), et range (wv&1)*4..+3 ----
  const int cqt  = wv >> 1;
  const int cet0 = (wv & 1) * 4;
  float ms[SPLITS], Ls[SPLITS];
  #pragma unroll
  for (int s2 = 0; s2 < SPLITS; ++s2) {
    ms[s2] = smML[((cqt * 2 + s2) * 2 + 0) * 16 + li];
    Ls[s2] = smML[((cqt * 2 + s2) * 2 + 1) * 16 + li];
  }
  float M = fmaxf(ms[0], ms[1]);
  float W[SPLITS];
  #pragma unroll
  for (int s2 = 0; s2 < SPLITS; ++s2) W[s2] = __builtin_amdgcn_exp2f(ms[s2] - M);
  const float rL = 1.f / (W[0] * Ls[0] + W[1] * Ls[1]);
  const int orow = b * NS + (within * 2 + cqt) * 16 + li;
  #pragma unroll
  for (int e2 = 0; e2 < 4; ++e2) {
    const int et = cet0 + e2;
    float4 v0 = smO[((cqt * 2 + 0) * 8 + et) * 64 + lane];
    float4 v1 = smO[((cqt * 2 + 1) * 8 + et) * 64 + lane];
    float4 acc;
    acc.x = (W[0] * v0.x + W[1] * v1.x) * rL;
    acc.y = (W[0] * v0.y + W[1] * v1.y) * rL;
    acc.z = (W[0] * v0.z + W[1] * v1.z) * rL;
    acc.w = (W[0] * v0.w + W[1] * v1.w) * rL;
    *(float4*)(Out + (size_t)orow * NE + et * 16 + g * 4) = acc;
  }
}

extern "C" void kernel_launch(void* const* d_in, const int* in_sizes, int n_in,
                              void* d_out, int out_size, void* d_ws, size_t ws_size,
                              hipStream_t stream) {
  const float* X  = (const float*)d_in[0];
  // d_in[1] = context : unused (per-row bias is softmax-invariant)
  const float* Wq = (const float*)d_in[2];
  const float* bq = (const float*)d_in[3];
  const float* Wk = (const float*)d_in[4];
  const float* bk = (const float*)d_in[5];
  const float* Wv = (const float*)d_in[6];
  const float* bv = (const float*)d_in[7];
  // d_in[8] = Wc, d_in[9] = bc : unused

  unsigned short* Qs  = (unsigned short*)d_ws;                // 4 MB
  unsigned short* Kd  = Qs + (size_t)NB * NS * NE;            // 4 MB
  unsigned short* VT  = Kd + (size_t)NB * NS * NE;            // 4 MB
  unsigned short* Wqb = VT + (size_t)NB * NS * NE;            // 32 KB x3
  unsigned short* Wkb = Wqb + NE * NE;
  unsigned short* Wvb = Wkb + NE * NE;

  prep_k<<<48, 256, 0, stream>>>(Wq, Wk, Wv, Wqb, Wkb, Wvb);
  qkv_proj_k<<<512, 256, 0, stream>>>(X, Wqb, bq, Wkb, bk, Wvb, bv, Qs, Kd, VT);
  attn_k<<<512, 256, 0, stream>>>(Qs, Kd, VT, (float*)d_out);
}